// Round 11
// baseline (198.752 us; speedup 1.0000x reference)
//
#include <hip/hip_runtime.h>

#define T_NUM 1024
#define DET_NUM 1024
#define E_NUM 65536
#define TWO_E 131072
#define N_NODES 2048
#define D_IN 512
#define D_EMB 256

__device__ __forceinline__ unsigned bf16r(float x) {
  const unsigned u = __float_as_uint(x);
  return (u + 0x7fffu + ((u >> 16) & 1u)) >> 16;  // RNE
}
__device__ __forceinline__ float bflo(unsigned p) { return __uint_as_float(p << 16); }
__device__ __forceinline__ float bfhi(unsigned p) { return __uint_as_float(p & 0xffff0000u); }
__device__ __forceinline__ void fma4(float4& a, float s, const float4 w) {
  a.x = fmaf(s, w.x, a.x); a.y = fmaf(s, w.y, a.y);
  a.z = fmaf(s, w.z, a.z); a.w = fmaf(s, w.w, a.w);
}

// ======== fused encoder + P1/P2/G1/G2 precompute (r10 structure). ========
__global__ __launch_bounds__(512) void k_enc_pg(
    const float* __restrict__ x, const float* __restrict__ W,
    const float* __restrict__ b, const float* __restrict__ coords,
    const float* __restrict__ W1a, const float* __restrict__ W1g,
    float* __restrict__ node, float* __restrict__ P1, float* __restrict__ P2,
    float* __restrict__ G1, float* __restrict__ G2) {
  __shared__ __align__(16) float xsh[4][D_IN];        // x rows (8 KB)
  __shared__ __align__(16) float pg[8][4][D_EMB];     // GEMM k-partials (32 KB)
  __shared__ __align__(16) float ns[4][D_EMB];        // final relu'd rows
  __shared__ float pp1[4][64], pp2[4][64];            // P-phase half partials
  const int tid = threadIdx.x;
  const int row0 = blockIdx.x * 4;
  // ---- stage x rows (coalesced: 512 thr x 1 float4 = 4 x 512 floats) ----
  {
    const int idx = tid * 4;
    const int r = idx >> 9, c = idx & 511;
    *reinterpret_cast<float4*>(&xsh[r][c]) =
        *reinterpret_cast<const float4*>(x + (size_t)(row0 + r) * D_IN + c);
  }
  __syncthreads();
  // ---- node GEMM: thread = (kq = wave 0..7 over 64 k, jq = tid&63) ----
  {
    const int kq = __builtin_amdgcn_readfirstlane(tid >> 6);
    const int jq = tid & 63;
    const float4* W4 = (const float4*)W;
    float4 a0 = make_float4(0.f, 0.f, 0.f, 0.f);
    float4 a1 = a0, a2 = a0, a3 = a0;
    const int kbeg = kq * 64;
    for (int k = kbeg; k < kbeg + 64; ++k) {
      const float4 w4 = W4[k * 64 + jq];
      fma4(a0, xsh[0][k], w4);
      fma4(a1, xsh[1][k], w4);
      fma4(a2, xsh[2][k], w4);
      fma4(a3, xsh[3][k], w4);
    }
    *reinterpret_cast<float4*>(&pg[kq][0][4 * jq]) = a0;
    *reinterpret_cast<float4*>(&pg[kq][1][4 * jq]) = a1;
    *reinterpret_cast<float4*>(&pg[kq][2][4 * jq]) = a2;
    *reinterpret_cast<float4*>(&pg[kq][3][4 * jq]) = a3;
  }
  __syncthreads();
  // ---- merge + bias + relu + store node/ns: thread = (r = tid>>7, 2 cols) --
  {
    const int r = tid >> 7, jc = tid & 127;
    float v0 = b[2 * jc + 0], v1 = b[2 * jc + 1];
#pragma unroll
    for (int kq = 0; kq < 8; kq++) {
      v0 += pg[kq][r][2 * jc + 0];
      v1 += pg[kq][r][2 * jc + 1];
    }
    v0 = fmaxf(v0, 0.f); v1 = fmaxf(v1, 0.f);
    *reinterpret_cast<float2*>(node + (size_t)(row0 + r) * D_EMB + 2 * jc) =
        make_float2(v0, v1);
    ns[r][2 * jc] = v0; ns[r][2 * jc + 1] = v1;
  }
  __syncthreads();
  // ---- P phase: 512 thr = 4 rows x 2 k-halves x 64 hh. q2 wave-uniform
  // ((tid>>6)&1) keeps W1a loads 256B-coalesced; halves merge via LDS. ----
  const int r2 = tid >> 7, q2 = (tid >> 6) & 1, hh = tid & 63;
  float a1 = 0.f, a2 = 0.f;
  {
    const int k0 = q2 * 128;
    for (int k = 0; k < 128; k += 4) {
      const float4 nv = *reinterpret_cast<const float4*>(&ns[r2][k0 + k]);
      a1 = fmaf(nv.x, W1a[(k0 + k + 0) * 64 + hh], a1);
      a1 = fmaf(nv.y, W1a[(k0 + k + 1) * 64 + hh], a1);
      a1 = fmaf(nv.z, W1a[(k0 + k + 2) * 64 + hh], a1);
      a1 = fmaf(nv.w, W1a[(k0 + k + 3) * 64 + hh], a1);
      a2 = fmaf(nv.x, W1a[(D_EMB + k0 + k + 0) * 64 + hh], a2);
      a2 = fmaf(nv.y, W1a[(D_EMB + k0 + k + 1) * 64 + hh], a2);
      a2 = fmaf(nv.z, W1a[(D_EMB + k0 + k + 2) * 64 + hh], a2);
      a2 = fmaf(nv.w, W1a[(D_EMB + k0 + k + 3) * 64 + hh], a2);
    }
    if (q2 == 1) { pp1[r2][hh] = a1; pp2[r2][hh] = a2; }
  }
  __syncthreads();
  if (q2 == 0) {
    P1[(size_t)(row0 + r2) * 64 + hh] = a1 + pp1[r2][hh];
    P2[(size_t)(row0 + r2) * 64 + hh] = a2 + pp2[r2][hh];
  }
  if (tid < 64) {
    const int r = tid >> 4, g = tid & 15;
    const int n = row0 + r;
    float g1 = 0.f, g2 = 0.f;
#pragma unroll
    for (int k = 0; k < 4; k++) {
      const float c = coords[(size_t)n * 4 + k];
      g1 = fmaf(c, W1g[k * 16 + g], g1);
      g2 = fmaf(c, W1g[(4 + k) * 16 + g], g2);
    }
    G1[(size_t)n * 16 + g] = g1;
    G2[(size_t)n * 16 + g] = g2;
  }
}

// ======== fused: edge MLP + msg + out GEMM + norms (r9 structure). ========
__global__ __launch_bounds__(512) void k_msg_out(
    const float* __restrict__ node,
    const float* __restrict__ P1, const float* __restrict__ P2,
    const float* __restrict__ G1, const float* __restrict__ G2,
    const float* __restrict__ b1a, const float* __restrict__ W2a, const float* __restrict__ b2a,
    const float* __restrict__ b1g, const float* __restrict__ W2g, const float* __restrict__ b2g,
    const float* __restrict__ W1f, const float* __restrict__ b1f,
    const float* __restrict__ W2f, const float* __restrict__ b2f,
    const float* __restrict__ Wn, const float* __restrict__ Wm,
    const float* __restrict__ bo, float* __restrict__ outE, float* __restrict__ nrm) {
  __shared__ __align__(16) float msp[2][4][D_EMB];  // msg partials (2 src-grps)
  __shared__ __align__(16) float ms[4][D_EMB];      // merged msg
  __shared__ __align__(16) float nsh[4][D_EMB];     // node rows (LDS broadcast)
  __shared__ __align__(16) float pg[8][4][D_EMB];   // GEMM k-partials (32 KB)
  __shared__ float wsh[4][64];
  __shared__ int ssh[4][64];
  __shared__ float pa1[4][64], pa2[4][64];          // half-1 staging partials
  __shared__ float redn[8];
  const int tid = threadIdx.x;
  const int h = __builtin_amdgcn_readfirstlane(tid >> 8);  // half (wave-uniform)
  const int j = tid & 255;
  const int row0 = blockIdx.x * 4;
  // ---- staging: edge weight, half the dot per thread (4 rows x 64 edges) --
  {
    const int r = (tid >> 6) & 3, o = tid & 63;
    const int n = row0 + r;
    int src;
    if (n < T_NUM) {              // tracklet: src = det node of reverse edge
      src = T_NUM + ((13 * n + o) & 1023);
    } else {                      // det d: src = tracklet t = 709(d-o)
      const int d = n - T_NUM;
      src = (709 * (d - o)) & 1023;
    }
    float a1p = 0.f, a2p = 0.f;
    const float4* p1 = (const float4*)(P1 + (size_t)src * 64) + h * 8;
    const float4* p2 = (const float4*)(P2 + (size_t)n * 64) + h * 8;
    const float4* b1 = (const float4*)b1a + h * 8;
    const float4* w2 = (const float4*)W2a + h * 8;
#pragma unroll
    for (int i = 0; i < 8; i++) {
      const float4 pa = p1[i], pb = p2[i], bb = b1[i], ww = w2[i];
      a1p += fmaxf(pa.x + pb.x + bb.x, 0.f) * ww.x + fmaxf(pa.y + pb.y + bb.y, 0.f) * ww.y +
             fmaxf(pa.z + pb.z + bb.z, 0.f) * ww.z + fmaxf(pa.w + pb.w + bb.w, 0.f) * ww.w;
    }
    const float4* g1 = (const float4*)(G1 + (size_t)src * 16) + h * 2;
    const float4* g2 = (const float4*)(G2 + (size_t)n * 16) + h * 2;
    const float4* bg = (const float4*)b1g + h * 2;
    const float4* wg = (const float4*)W2g + h * 2;
#pragma unroll
    for (int i = 0; i < 2; i++) {
      const float4 pa = g1[i], pb = g2[i], bb = bg[i], ww = wg[i];
      a2p += fmaxf(pa.x + pb.x + bb.x, 0.f) * ww.x + fmaxf(pa.y + pb.y + bb.y, 0.f) * ww.y +
             fmaxf(pa.z + pb.z + bb.z, 0.f) * ww.z + fmaxf(pa.w + pb.w + bb.w, 0.f) * ww.w;
    }
    if (h == 1) { pa1[r][o] = a1p; pa2[r][o] = a2p; ssh[r][o] = src; }
    else        { wsh[r][o] = a1p; pg[0][r][o] = a2p; }   // stash h0 partials
  }
  __syncthreads();
  if (h == 0) {          // finalize edge weight
    const int r = (tid >> 6) & 3, o = tid & 63;
    const float a1 = wsh[r][o] + pa1[r][o] + b2a[0];
    const float a2 = pg[0][r][o] + pa2[r][o] + b2g[0];
    float acc = b2f[0];
#pragma unroll
    for (int jj = 0; jj < 8; jj++) {
      const float hv = fmaxf(a1 * W1f[jj] + a2 * W1f[8 + jj] + b1f[jj], 0.f);
      acc = fmaf(hv, W2f[jj], acc);
    }
    wsh[r][o] = acc;
  } else {               // stage node rows for the GEMM (coalesced)
#pragma unroll
    for (int rr = 0; rr < 4; rr++)
      nsh[rr][j] = node[(size_t)(row0 + rr) * D_EMB + j];
  }
  __syncthreads();
  // ---- msg: quad-gather. thread = (s = tid>>8, r = (tid>>6)&3, qd = tid&63)
  // 32 srcs x 1 row x 4 cols; wave = fixed (s,r), 64 qd-lanes read 1KB
  // contiguous per src row (fully coalesced). ----
  {
    const int s = tid >> 8;
    const int r = (tid >> 6) & 3;
    const int qd = tid & 63;
    const int i0 = s * 32;
    float ax = 0.f, ay = 0.f, az = 0.f, aw = 0.f;
#pragma unroll 4
    for (int i = 0; i < 32; i++) {
      const float w = wsh[r][i0 + i];
      const float4 nv = *reinterpret_cast<const float4*>(
          node + (size_t)ssh[r][i0 + i] * D_EMB + 4 * qd);
      ax = fmaf(w, nv.x, ax); ay = fmaf(w, nv.y, ay);
      az = fmaf(w, nv.z, az); aw = fmaf(w, nv.w, aw);
    }
    *reinterpret_cast<float4*>(&msp[s][r][4 * qd]) = make_float4(ax, ay, az, aw);
  }
  __syncthreads();
  {
    float* m0 = &ms[0][0];
    const float* s0 = &msp[0][0][0];
    const float* s1 = &msp[1][0][0];
    m0[tid] = s0[tid] + s1[tid];
    m0[tid + 512] = s0[tid + 512] + s1[tid + 512];
  }
  __syncthreads();
  // ---- out GEMM: thread = (kq = wave id 0..7 over 32 k each, jq = tid&63).
  // Per k: 2 dwordx4 W loads + 8 LDS broadcast scalars + 32 FMA. ----
  {
    const int kq = __builtin_amdgcn_readfirstlane(tid >> 6);
    const int jq = tid & 63;
    const float4* Wn4 = (const float4*)Wn;
    const float4* Wm4 = (const float4*)Wm;
    float4 a0 = make_float4(0.f, 0.f, 0.f, 0.f);
    float4 a1 = a0, a2 = a0, a3 = a0;
    const int kbeg = kq * 32;
    for (int k = kbeg; k < kbeg + 32; ++k) {
      const float4 wn = Wn4[k * 64 + jq];
      const float4 wm = Wm4[k * 64 + jq];
      const float n0 = nsh[0][k], m0v = ms[0][k];
      const float n1 = nsh[1][k], m1v = ms[1][k];
      const float n2 = nsh[2][k], m2v = ms[2][k];
      const float n3 = nsh[3][k], m3v = ms[3][k];
      fma4(a0, n0, wn); fma4(a0, m0v, wm);
      fma4(a1, n1, wn); fma4(a1, m1v, wm);
      fma4(a2, n2, wn); fma4(a2, m2v, wm);
      fma4(a3, n3, wn); fma4(a3, m3v, wm);
    }
    *reinterpret_cast<float4*>(&pg[kq][0][4 * jq]) = a0;
    *reinterpret_cast<float4*>(&pg[kq][1][4 * jq]) = a1;
    *reinterpret_cast<float4*>(&pg[kq][2][4 * jq]) = a2;
    *reinterpret_cast<float4*>(&pg[kq][3][4 * jq]) = a3;
  }
  __syncthreads();
  // ---- merge + relu + store + norms. thread = (r = tid>>7, 2 cols). Wave
  // spans a single row -> shfl reduce per wave; redn[8] (2 waves/row). ----
  {
    const int r = tid >> 7, jc = tid & 127;
    const int lane = tid & 63, wid = tid >> 6;
    float v0 = bo[2 * jc + 0], v1 = bo[2 * jc + 1];
#pragma unroll
    for (int kq = 0; kq < 8; kq++) {
      v0 += pg[kq][r][2 * jc + 0];
      v1 += pg[kq][r][2 * jc + 1];
    }
    v0 = fmaxf(v0, 0.f); v1 = fmaxf(v1, 0.f);
    *reinterpret_cast<float2*>(outE + (size_t)(row0 + r) * D_EMB + 2 * jc) =
        make_float2(v0, v1);
    float sq = v0 * v0 + v1 * v1;
#pragma unroll
    for (int oo = 32; oo > 0; oo >>= 1) sq += __shfl_down(sq, oo, 64);
    if (lane == 0) redn[wid] = sq;
  }
  __syncthreads();
  if (tid < 4)
    nrm[row0 + tid] = sqrtf(redn[2 * tid] + redn[2 * tid + 1]);
}

// ======== affinity -> row band Kbp (f32) + transposed col band KTg (bf16) ==
// One block per tracklet t (1024 blocks -> 4 blocks/CU), 256 thr
// = 64 edges x 4 chunks. out[s] staged in LDS; threads 0..63 finalize.
__global__ __launch_bounds__(256) void k_aff(
    const float* __restrict__ outE, const float* __restrict__ nrm,
    const float* __restrict__ cov,
    const float* __restrict__ W1c, const float* __restrict__ b1c,
    const float* __restrict__ W2c, const float* __restrict__ b2c,
    float* __restrict__ Kbp, unsigned short* __restrict__ KTg) {
  __shared__ __align__(16) float4 oas[64];      // out[s] row (256 f)
  __shared__ float psum[4][64];
  const int t = blockIdx.x;
  const int tid = threadIdx.x;
  const int o = tid & 63, c = tid >> 6;         // edge o, chunk c (wave-uniform)
  const int s = t;
  if (tid < 64) oas[tid] = ((const float4*)(outE + (size_t)s * D_EMB))[tid];
  __syncthreads();
  const int d = (13 * t + o) & 1023;
  const int dn = T_NUM + d;
  {
    const float4* ob = (const float4*)(outE + (size_t)dn * D_EMB) + c * 16;
    const float4* oa = oas + c * 16;
    float dot = 0.f;
#pragma unroll
    for (int i = 0; i < 16; i++) {
      const float4 a = oa[i], bq = ob[i];
      dot += a.x * bq.x + a.y * bq.y + a.z * bq.z + a.w * bq.w;
    }
    psum[c][o] = dot;
  }
  __syncthreads();
  if (tid < 64) {
    const float dot = psum[0][o] + psum[1][o] + psum[2][o] + psum[3][o];
    const float cosv = dot / fmaxf(nrm[s] * nrm[dn], 1e-6f);
    const float4 A = ((const float4*)cov)[s];
    const float4 B = ((const float4*)cov)[dn];
    const float ltx = fmaxf(A.x, B.x), lty = fmaxf(A.y, B.y);
    const float rbx = fminf(A.z, B.z), rby = fminf(A.w, B.w);
    const float wx = fmaxf(rbx - ltx, 0.f), wy = fmaxf(rby - lty, 0.f);
    const float inter = wx * wy;
    const float areaA = (A.z - A.x) * (A.w - A.y);
    const float areaB = (B.z - B.x) * (B.w - B.y);
    const float iou = inter / (areaA + areaB - inter + 1e-9f);
    float aff = b2c[0];
#pragma unroll
    for (int jj = 0; jj < 8; jj++) {
      const float h = fmaxf(cosv * W1c[jj] + iou * W1c[8 + jj] + b1c[jj], 0.f);
      aff = fmaf(h, W2c[jj], aff);
    }
    const float Kv = __expf(aff * 5.0f);
    const int tp = (13 * s) & 1023;
    Kbp[tp * 68 + (tp & 3) + o] = Kv;
    if (o < 4) {
      const int pr = (o < (tp & 3)) ? o : o + 64;   // the 4 pad slots of row tp
      Kbp[tp * 68 + pr] = 0.f;
    }
    const int cbase = (((d & 1022) + 960) & 1023) & ~3;
    const int rho = (((d + 961) & 1023) - cbase) & 1023;   // 1..4
    KTg[d * 72 + rho + 63 - o] = (unsigned short)bf16r(Kv);
    if (o < 8) {
      const int slot = (o < rho) ? o : o + 64;      // pads: [0,rho) U [rho+64,72)
      KTg[d * 72 + slot] = 0;
    }
  }
}

// ======== Sinkhorn v3 (r11): 1024 thr, 1 row + 1 col per thread.
// r1/r2's 1024-thr attempt spilled: 70 persistent regs (kr[34]+kt[36])
// under the 64-VGPR cap this toolchain pins on 1024-thr kernels. With KT
// in LDS (r3 layout, now [9][1024]) the persistent set is kr[34]+4 ~ 38,
// peak ~58 < 64 -> no spill expected. 16 waves = 4 waves/SIMD on the one
// CU (vs 2 at 512 thr): 2x latency hiding, half the per-thread chain.
// Math byte-identical to the (correct-but-spilled) r1 kernel.
// gt-copy overlay: blocks 1..256 x 1024 thr x 1 float4 (free overlap).
__global__ __launch_bounds__(1024) void k_sinkhorn(
    const float* __restrict__ Kbp, const unsigned short* __restrict__ KTg,
    float* __restrict__ ug, float* __restrict__ vg,
    const float* __restrict__ gt, float* __restrict__ out) {
  if (blockIdx.x != 0) {   // gt copy: blocks 1..256
    const size_t idx = (size_t)(blockIdx.x - 1) * 1024 + threadIdx.x;
    ((float4*)out)[(size_t)T_NUM * 256 + idx] = ((const float4*)gt)[idx];
    return;
  }
  __shared__ __align__(16) float u_lds[1092];   // replicated: [1024+i]=[i], i<68
  __shared__ __align__(16) float v_lds[1092];
  __shared__ float red_u[16];
  __shared__ float red_v[16];
  __shared__ __align__(16) uint4 ktl[9][1024];  // KT band, 144 KB
  const int tid = threadIdx.x;                  // row = tid (t'), col = tid (d)
  const int lane = tid & 63, wid = tid >> 6;
  unsigned kr[34];                              // 68 bf16 row-K slots (34 regs)
  {
    const float4* sp = (const float4*)(Kbp + (size_t)tid * 68);
#pragma unroll
    for (int c = 0; c < 17; c++) {
      const float4 f = sp[c];
      kr[2 * c]     = bf16r(f.x) | (bf16r(f.y) << 16);
      kr[2 * c + 1] = bf16r(f.z) | (bf16r(f.w) << 16);
    }
  }
  {
    // stage KT band: thread reads its col's 144B (9 uint4), writes
    // lane-contiguous LDS. One-time; conflict-free on read side.
    const uint4* g = (const uint4*)KTg;
#pragma unroll
    for (int q = 0; q < 9; q++) ktl[q][tid] = g[tid * 9 + q];
  }
  const int qa = tid & ~3;                        // row v-window base (floats)
  const int cb = (((tid & ~1) + 960) & 1023) & ~3; // col u-window base
  float u = 1.f, v = 1.f, u_sl = 1.f, v_sl = 1.f;
  v_lds[tid] = 1.f;
  if (tid < 68) v_lds[1024 + tid] = 1.f;
  if (tid < 16) red_v[tid] = 64.f;              // 64 lanes x 1 col x 1.0
  const float slack = 0.36787944117144233f;     // exp(SLACK*LAM) = exp(-1)
  __syncthreads();
#pragma unroll 1
  for (int it = 0; it < 8; ++it) {
    // ---- row phase: 68-slot v-window from LDS (4-lane broadcast groups)
    const float4* vq = (const float4*)(v_lds + qa);
    float a0 = 0.f, a1 = 0.f;
#pragma unroll
    for (int c = 0; c < 17; c++) {
      const float4 v4 = vq[c];
      unsigned p = kr[2 * c];
      a0 = fmaf(bflo(p), v4.x, a0); a0 = fmaf(bfhi(p), v4.y, a0);
      p = kr[2 * c + 1];
      a1 = fmaf(bflo(p), v4.z, a1); a1 = fmaf(bfhi(p), v4.w, a1);
    }
    float sumv = 0.f;
#pragma unroll
    for (int i = 0; i < 16; i++) sumv += red_v[i];
    const float s = a0 + a1 + slack * v_sl;
    u = u / (u * s + 1e-9f);
    u_sl = u_sl / (u_sl * slack * (sumv + v_sl) + 1e-9f);
    u_lds[tid] = u;
    if (tid < 68) u_lds[1024 + tid] = u;
    float usum = u;
#pragma unroll
    for (int o = 32; o > 0; o >>= 1) usum += __shfl_down(usum, o, 64);
    if (lane == 0) red_u[wid] = usum;
    __syncthreads();
    // ---- col phase: KT from LDS (lane-contiguous), 72-slot u-window
    const float4* uq = (const float4*)(u_lds + cb);
    float t0 = 0.f, t1 = 0.f;
#pragma unroll 3
    for (int q = 0; q < 9; q++) {
      const uint4 A = ktl[q][tid];
      const float4 ua = uq[2 * q];
      const float4 ub = uq[2 * q + 1];
      t0 = fmaf(bflo(A.x), ua.x, t0); t0 = fmaf(bfhi(A.x), ua.y, t0);
      t0 = fmaf(bflo(A.y), ua.z, t0); t0 = fmaf(bfhi(A.y), ua.w, t0);
      t1 = fmaf(bflo(A.z), ub.x, t1); t1 = fmaf(bfhi(A.z), ub.y, t1);
      t1 = fmaf(bflo(A.w), ub.z, t1); t1 = fmaf(bfhi(A.w), ub.w, t1);
    }
    float sumu = 0.f;
#pragma unroll
    for (int i = 0; i < 16; i++) sumu += red_u[i];
    const float tv = t0 + t1 + slack * u_sl;
    v = v / (v * tv + 1e-9f);
    v_sl = v_sl / (v_sl * slack * (sumu + u_sl) + 1e-9f);
    v_lds[tid] = v;
    if (tid < 68) v_lds[1024 + tid] = v;
    float vsum = v;
#pragma unroll
    for (int o = 32; o > 0; o >>= 1) vsum += __shfl_down(vsum, o, 64);
    if (lane == 0) red_v[wid] = vsum;
    __syncthreads();
  }
  ug[tid] = u;                                  // row tid (t' space)
  vg[tid] = v;                                  // col tid (d space)
}

// ======== dense final write (product only; gt copy moved to k_sinkhorn) ====
__global__ __launch_bounds__(256) void k_final(
    const float* __restrict__ Kbp, const float* __restrict__ ug,
    const float* __restrict__ vg, float* __restrict__ out) {
  const int t = blockIdx.x;
  const int tp = (13 * t) & 1023;
  const float u = ug[tp];
  const float* krow = Kbp + (size_t)tp * 68 + (tp & 3);
  const int d0 = threadIdx.x * 4;
  const float4 v4 = ((const float4*)vg)[threadIdx.x];
  float4 o4;
  const int m0 = (d0 - tp) & 1023;
  const int m1 = (d0 + 1 - tp) & 1023;
  const int m2 = (d0 + 2 - tp) & 1023;
  const int m3 = (d0 + 3 - tp) & 1023;
  o4.x = (m0 < 64) ? u * krow[m0] * v4.x : 0.f;
  o4.y = (m1 < 64) ? u * krow[m1] * v4.y : 0.f;
  o4.z = (m2 < 64) ? u * krow[m2] * v4.z : 0.f;
  o4.w = (m3 < 64) ? u * krow[m3] * v4.w : 0.f;
  ((float4*)out)[(size_t)t * 256 + threadIdx.x] = o4;
  if (t == 0 && threadIdx.x == 0) {
    out[(size_t)2 * T_NUM * DET_NUM] = 1024.0f;      // det_num
    out[(size_t)2 * T_NUM * DET_NUM + 1] = 1024.0f;  // tracklet_num
  }
}

extern "C" void kernel_launch(void* const* d_in, const int* in_sizes, int n_in,
                              void* d_out, int out_size, void* d_ws, size_t ws_size,
                              hipStream_t stream) {
  const float* x      = (const float*)d_in[0];
  const float* coords = (const float*)d_in[1];
  const float* cov    = (const float*)d_in[2];
  const float* gt     = (const float*)d_in[3];
  const float* W_enc  = (const float*)d_in[5];
  const float* b_enc  = (const float*)d_in[6];
  const float* W1a    = (const float*)d_in[7];
  const float* b1a    = (const float*)d_in[8];
  const float* W2a    = (const float*)d_in[9];
  const float* b2a    = (const float*)d_in[10];
  const float* W1g    = (const float*)d_in[11];
  const float* b1g    = (const float*)d_in[12];
  const float* W2g    = (const float*)d_in[13];
  const float* b2g    = (const float*)d_in[14];
  const float* W1f    = (const float*)d_in[15];
  const float* b1f    = (const float*)d_in[16];
  const float* W2f    = (const float*)d_in[17];
  const float* b2f    = (const float*)d_in[18];
  const float* Wn     = (const float*)d_in[19];
  const float* Wm     = (const float*)d_in[20];
  const float* bo     = (const float*)d_in[21];
  const float* W1c    = (const float*)d_in[22];
  const float* b1c    = (const float*)d_in[23];
  const float* W2c    = (const float*)d_in[24];
  const float* b2c    = (const float*)d_in[25];

  char* ws = (char*)d_ws;
  size_t off = 0;
  auto alloc = [&](size_t bytes) {
    char* p = ws + off;
    off = (off + bytes + 255) & ~(size_t)255;
    return p;
  };
  float* node  = (float*)alloc((size_t)N_NODES * D_EMB * 4);
  float* P1    = (float*)alloc((size_t)N_NODES * 64 * 4);
  float* P2    = (float*)alloc((size_t)N_NODES * 64 * 4);
  float* G1    = (float*)alloc((size_t)N_NODES * 16 * 4);
  float* G2    = (float*)alloc((size_t)N_NODES * 16 * 4);
  float* outE  = (float*)alloc((size_t)N_NODES * D_EMB * 4);
  float* nrm   = (float*)alloc((size_t)N_NODES * 4);
  float* Kbp   = (float*)alloc((size_t)1024 * 68 * 4);
  unsigned short* KTg = (unsigned short*)alloc((size_t)1024 * 72 * 2);
  float* ug    = (float*)alloc(1024 * 4);
  float* vg    = (float*)alloc(1024 * 4);
  float* out   = (float*)d_out;

  k_enc_pg<<<N_NODES / 4, 512, 0, stream>>>(x, W_enc, b_enc, coords, W1a, W1g,
                                            node, P1, P2, G1, G2);
  k_msg_out<<<N_NODES / 4, 512, 0, stream>>>(node, P1, P2, G1, G2,
                                             b1a, W2a, b2a, b1g, W2g, b2g,
                                             W1f, b1f, W2f, b2f,
                                             Wn, Wm, bo, outE, nrm);
  k_aff<<<T_NUM, 256, 0, stream>>>(outE, nrm, cov, W1c, b1c, W2c, b2c,
                                   Kbp, KTg);
  k_sinkhorn<<<257, 1024, 0, stream>>>(Kbp, KTg, ug, vg, gt, out);
  k_final<<<T_NUM, 256, 0, stream>>>(Kbp, ug, vg, out);
}

// Round 12
// 193.149 us; speedup vs baseline: 1.0290x; 1.0290x over previous
//
#include <hip/hip_runtime.h>

#define T_NUM 1024
#define DET_NUM 1024
#define E_NUM 65536
#define TWO_E 131072
#define N_NODES 2048
#define D_IN 512
#define D_EMB 256

__device__ __forceinline__ unsigned bf16r(float x) {
  const unsigned u = __float_as_uint(x);
  return (u + 0x7fffu + ((u >> 16) & 1u)) >> 16;  // RNE
}
__device__ __forceinline__ float bflo(unsigned p) { return __uint_as_float(p << 16); }
__device__ __forceinline__ float bfhi(unsigned p) { return __uint_as_float(p & 0xffff0000u); }
__device__ __forceinline__ void fma4(float4& a, float s, const float4 w) {
  a.x = fmaf(s, w.x, a.x); a.y = fmaf(s, w.y, a.y);
  a.z = fmaf(s, w.z, a.z); a.w = fmaf(s, w.w, a.w);
}

// ======== fused encoder + P1/P2/G1/G2 precompute (r10 structure). ========
__global__ __launch_bounds__(512) void k_enc_pg(
    const float* __restrict__ x, const float* __restrict__ W,
    const float* __restrict__ b, const float* __restrict__ coords,
    const float* __restrict__ W1a, const float* __restrict__ W1g,
    float* __restrict__ node, float* __restrict__ P1, float* __restrict__ P2,
    float* __restrict__ G1, float* __restrict__ G2) {
  __shared__ __align__(16) float xsh[4][D_IN];        // x rows (8 KB)
  __shared__ __align__(16) float pg[8][4][D_EMB];     // GEMM k-partials (32 KB)
  __shared__ __align__(16) float ns[4][D_EMB];        // final relu'd rows
  __shared__ float pp1[4][64], pp2[4][64];            // P-phase half partials
  const int tid = threadIdx.x;
  const int row0 = blockIdx.x * 4;
  // ---- stage x rows (coalesced: 512 thr x 1 float4 = 4 x 512 floats) ----
  {
    const int idx = tid * 4;
    const int r = idx >> 9, c = idx & 511;
    *reinterpret_cast<float4*>(&xsh[r][c]) =
        *reinterpret_cast<const float4*>(x + (size_t)(row0 + r) * D_IN + c);
  }
  __syncthreads();
  // ---- node GEMM: thread = (kq = wave 0..7 over 64 k, jq = tid&63) ----
  {
    const int kq = __builtin_amdgcn_readfirstlane(tid >> 6);
    const int jq = tid & 63;
    const float4* W4 = (const float4*)W;
    float4 a0 = make_float4(0.f, 0.f, 0.f, 0.f);
    float4 a1 = a0, a2 = a0, a3 = a0;
    const int kbeg = kq * 64;
    for (int k = kbeg; k < kbeg + 64; ++k) {
      const float4 w4 = W4[k * 64 + jq];
      fma4(a0, xsh[0][k], w4);
      fma4(a1, xsh[1][k], w4);
      fma4(a2, xsh[2][k], w4);
      fma4(a3, xsh[3][k], w4);
    }
    *reinterpret_cast<float4*>(&pg[kq][0][4 * jq]) = a0;
    *reinterpret_cast<float4*>(&pg[kq][1][4 * jq]) = a1;
    *reinterpret_cast<float4*>(&pg[kq][2][4 * jq]) = a2;
    *reinterpret_cast<float4*>(&pg[kq][3][4 * jq]) = a3;
  }
  __syncthreads();
  // ---- merge + bias + relu + store node/ns: thread = (r = tid>>7, 2 cols) --
  {
    const int r = tid >> 7, jc = tid & 127;
    float v0 = b[2 * jc + 0], v1 = b[2 * jc + 1];
#pragma unroll
    for (int kq = 0; kq < 8; kq++) {
      v0 += pg[kq][r][2 * jc + 0];
      v1 += pg[kq][r][2 * jc + 1];
    }
    v0 = fmaxf(v0, 0.f); v1 = fmaxf(v1, 0.f);
    *reinterpret_cast<float2*>(node + (size_t)(row0 + r) * D_EMB + 2 * jc) =
        make_float2(v0, v1);
    ns[r][2 * jc] = v0; ns[r][2 * jc + 1] = v1;
  }
  __syncthreads();
  // ---- P phase: 512 thr = 4 rows x 2 k-halves x 64 hh. q2 wave-uniform
  // ((tid>>6)&1) keeps W1a loads 256B-coalesced; halves merge via LDS. ----
  const int r2 = tid >> 7, q2 = (tid >> 6) & 1, hh = tid & 63;
  float a1 = 0.f, a2 = 0.f;
  {
    const int k0 = q2 * 128;
    for (int k = 0; k < 128; k += 4) {
      const float4 nv = *reinterpret_cast<const float4*>(&ns[r2][k0 + k]);
      a1 = fmaf(nv.x, W1a[(k0 + k + 0) * 64 + hh], a1);
      a1 = fmaf(nv.y, W1a[(k0 + k + 1) * 64 + hh], a1);
      a1 = fmaf(nv.z, W1a[(k0 + k + 2) * 64 + hh], a1);
      a1 = fmaf(nv.w, W1a[(k0 + k + 3) * 64 + hh], a1);
      a2 = fmaf(nv.x, W1a[(D_EMB + k0 + k + 0) * 64 + hh], a2);
      a2 = fmaf(nv.y, W1a[(D_EMB + k0 + k + 1) * 64 + hh], a2);
      a2 = fmaf(nv.z, W1a[(D_EMB + k0 + k + 2) * 64 + hh], a2);
      a2 = fmaf(nv.w, W1a[(D_EMB + k0 + k + 3) * 64 + hh], a2);
    }
    if (q2 == 1) { pp1[r2][hh] = a1; pp2[r2][hh] = a2; }
  }
  __syncthreads();
  if (q2 == 0) {
    P1[(size_t)(row0 + r2) * 64 + hh] = a1 + pp1[r2][hh];
    P2[(size_t)(row0 + r2) * 64 + hh] = a2 + pp2[r2][hh];
  }
  if (tid < 64) {
    const int r = tid >> 4, g = tid & 15;
    const int n = row0 + r;
    float g1 = 0.f, g2 = 0.f;
#pragma unroll
    for (int k = 0; k < 4; k++) {
      const float c = coords[(size_t)n * 4 + k];
      g1 = fmaf(c, W1g[k * 16 + g], g1);
      g2 = fmaf(c, W1g[(4 + k) * 16 + g], g2);
    }
    G1[(size_t)n * 16 + g] = g1;
    G2[(size_t)n * 16 + g] = g2;
  }
}

// ======== fused: edge MLP + msg + out GEMM + norms (r9 structure). ========
__global__ __launch_bounds__(512) void k_msg_out(
    const float* __restrict__ node,
    const float* __restrict__ P1, const float* __restrict__ P2,
    const float* __restrict__ G1, const float* __restrict__ G2,
    const float* __restrict__ b1a, const float* __restrict__ W2a, const float* __restrict__ b2a,
    const float* __restrict__ b1g, const float* __restrict__ W2g, const float* __restrict__ b2g,
    const float* __restrict__ W1f, const float* __restrict__ b1f,
    const float* __restrict__ W2f, const float* __restrict__ b2f,
    const float* __restrict__ Wn, const float* __restrict__ Wm,
    const float* __restrict__ bo, float* __restrict__ outE, float* __restrict__ nrm) {
  __shared__ __align__(16) float msp[2][4][D_EMB];  // msg partials (2 src-grps)
  __shared__ __align__(16) float ms[4][D_EMB];      // merged msg
  __shared__ __align__(16) float nsh[4][D_EMB];     // node rows (LDS broadcast)
  __shared__ __align__(16) float pg[8][4][D_EMB];   // GEMM k-partials (32 KB)
  __shared__ float wsh[4][64];
  __shared__ int ssh[4][64];
  __shared__ float pa1[4][64], pa2[4][64];          // half-1 staging partials
  __shared__ float redn[8];
  const int tid = threadIdx.x;
  const int h = __builtin_amdgcn_readfirstlane(tid >> 8);  // half (wave-uniform)
  const int j = tid & 255;
  const int row0 = blockIdx.x * 4;
  // ---- staging: edge weight, half the dot per thread (4 rows x 64 edges) --
  {
    const int r = (tid >> 6) & 3, o = tid & 63;
    const int n = row0 + r;
    int src;
    if (n < T_NUM) {              // tracklet: src = det node of reverse edge
      src = T_NUM + ((13 * n + o) & 1023);
    } else {                      // det d: src = tracklet t = 709(d-o)
      const int d = n - T_NUM;
      src = (709 * (d - o)) & 1023;
    }
    float a1p = 0.f, a2p = 0.f;
    const float4* p1 = (const float4*)(P1 + (size_t)src * 64) + h * 8;
    const float4* p2 = (const float4*)(P2 + (size_t)n * 64) + h * 8;
    const float4* b1 = (const float4*)b1a + h * 8;
    const float4* w2 = (const float4*)W2a + h * 8;
#pragma unroll
    for (int i = 0; i < 8; i++) {
      const float4 pa = p1[i], pb = p2[i], bb = b1[i], ww = w2[i];
      a1p += fmaxf(pa.x + pb.x + bb.x, 0.f) * ww.x + fmaxf(pa.y + pb.y + bb.y, 0.f) * ww.y +
             fmaxf(pa.z + pb.z + bb.z, 0.f) * ww.z + fmaxf(pa.w + pb.w + bb.w, 0.f) * ww.w;
    }
    const float4* g1 = (const float4*)(G1 + (size_t)src * 16) + h * 2;
    const float4* g2 = (const float4*)(G2 + (size_t)n * 16) + h * 2;
    const float4* bg = (const float4*)b1g + h * 2;
    const float4* wg = (const float4*)W2g + h * 2;
#pragma unroll
    for (int i = 0; i < 2; i++) {
      const float4 pa = g1[i], pb = g2[i], bb = bg[i], ww = wg[i];
      a2p += fmaxf(pa.x + pb.x + bb.x, 0.f) * ww.x + fmaxf(pa.y + pb.y + bb.y, 0.f) * ww.y +
             fmaxf(pa.z + pb.z + bb.z, 0.f) * ww.z + fmaxf(pa.w + pb.w + bb.w, 0.f) * ww.w;
    }
    if (h == 1) { pa1[r][o] = a1p; pa2[r][o] = a2p; ssh[r][o] = src; }
    else        { wsh[r][o] = a1p; pg[0][r][o] = a2p; }   // stash h0 partials
  }
  __syncthreads();
  if (h == 0) {          // finalize edge weight
    const int r = (tid >> 6) & 3, o = tid & 63;
    const float a1 = wsh[r][o] + pa1[r][o] + b2a[0];
    const float a2 = pg[0][r][o] + pa2[r][o] + b2g[0];
    float acc = b2f[0];
#pragma unroll
    for (int jj = 0; jj < 8; jj++) {
      const float hv = fmaxf(a1 * W1f[jj] + a2 * W1f[8 + jj] + b1f[jj], 0.f);
      acc = fmaf(hv, W2f[jj], acc);
    }
    wsh[r][o] = acc;
  } else {               // stage node rows for the GEMM (coalesced)
#pragma unroll
    for (int rr = 0; rr < 4; rr++)
      nsh[rr][j] = node[(size_t)(row0 + rr) * D_EMB + j];
  }
  __syncthreads();
  // ---- msg: quad-gather. thread = (s = tid>>8, r = (tid>>6)&3, qd = tid&63)
  // 32 srcs x 1 row x 4 cols; wave = fixed (s,r), 64 qd-lanes read 1KB
  // contiguous per src row (fully coalesced). ----
  {
    const int s = tid >> 8;
    const int r = (tid >> 6) & 3;
    const int qd = tid & 63;
    const int i0 = s * 32;
    float ax = 0.f, ay = 0.f, az = 0.f, aw = 0.f;
#pragma unroll 4
    for (int i = 0; i < 32; i++) {
      const float w = wsh[r][i0 + i];
      const float4 nv = *reinterpret_cast<const float4*>(
          node + (size_t)ssh[r][i0 + i] * D_EMB + 4 * qd);
      ax = fmaf(w, nv.x, ax); ay = fmaf(w, nv.y, ay);
      az = fmaf(w, nv.z, az); aw = fmaf(w, nv.w, aw);
    }
    *reinterpret_cast<float4*>(&msp[s][r][4 * qd]) = make_float4(ax, ay, az, aw);
  }
  __syncthreads();
  {
    float* m0 = &ms[0][0];
    const float* s0 = &msp[0][0][0];
    const float* s1 = &msp[1][0][0];
    m0[tid] = s0[tid] + s1[tid];
    m0[tid + 512] = s0[tid + 512] + s1[tid + 512];
  }
  __syncthreads();
  // ---- out GEMM: thread = (kq = wave id 0..7 over 32 k each, jq = tid&63).
  // Per k: 2 dwordx4 W loads + 8 LDS broadcast scalars + 32 FMA. ----
  {
    const int kq = __builtin_amdgcn_readfirstlane(tid >> 6);
    const int jq = tid & 63;
    const float4* Wn4 = (const float4*)Wn;
    const float4* Wm4 = (const float4*)Wm;
    float4 a0 = make_float4(0.f, 0.f, 0.f, 0.f);
    float4 a1 = a0, a2 = a0, a3 = a0;
    const int kbeg = kq * 32;
    for (int k = kbeg; k < kbeg + 32; ++k) {
      const float4 wn = Wn4[k * 64 + jq];
      const float4 wm = Wm4[k * 64 + jq];
      const float n0 = nsh[0][k], m0v = ms[0][k];
      const float n1 = nsh[1][k], m1v = ms[1][k];
      const float n2 = nsh[2][k], m2v = ms[2][k];
      const float n3 = nsh[3][k], m3v = ms[3][k];
      fma4(a0, n0, wn); fma4(a0, m0v, wm);
      fma4(a1, n1, wn); fma4(a1, m1v, wm);
      fma4(a2, n2, wn); fma4(a2, m2v, wm);
      fma4(a3, n3, wn); fma4(a3, m3v, wm);
    }
    *reinterpret_cast<float4*>(&pg[kq][0][4 * jq]) = a0;
    *reinterpret_cast<float4*>(&pg[kq][1][4 * jq]) = a1;
    *reinterpret_cast<float4*>(&pg[kq][2][4 * jq]) = a2;
    *reinterpret_cast<float4*>(&pg[kq][3][4 * jq]) = a3;
  }
  __syncthreads();
  // ---- merge + relu + store + norms. thread = (r = tid>>7, 2 cols). Wave
  // spans a single row -> shfl reduce per wave; redn[8] (2 waves/row). ----
  {
    const int r = tid >> 7, jc = tid & 127;
    const int lane = tid & 63, wid = tid >> 6;
    float v0 = bo[2 * jc + 0], v1 = bo[2 * jc + 1];
#pragma unroll
    for (int kq = 0; kq < 8; kq++) {
      v0 += pg[kq][r][2 * jc + 0];
      v1 += pg[kq][r][2 * jc + 1];
    }
    v0 = fmaxf(v0, 0.f); v1 = fmaxf(v1, 0.f);
    *reinterpret_cast<float2*>(outE + (size_t)(row0 + r) * D_EMB + 2 * jc) =
        make_float2(v0, v1);
    float sq = v0 * v0 + v1 * v1;
#pragma unroll
    for (int oo = 32; oo > 0; oo >>= 1) sq += __shfl_down(sq, oo, 64);
    if (lane == 0) redn[wid] = sq;
  }
  __syncthreads();
  if (tid < 4)
    nrm[row0 + tid] = sqrtf(redn[2 * tid] + redn[2 * tid + 1]);
}

// ======== affinity -> row band Kbp (f32) + transposed col band KTg (bf16) ==
// One block per tracklet t (1024 blocks -> 4 blocks/CU), 256 thr
// = 64 edges x 4 chunks. out[s] staged in LDS; threads 0..63 finalize.
__global__ __launch_bounds__(256) void k_aff(
    const float* __restrict__ outE, const float* __restrict__ nrm,
    const float* __restrict__ cov,
    const float* __restrict__ W1c, const float* __restrict__ b1c,
    const float* __restrict__ W2c, const float* __restrict__ b2c,
    float* __restrict__ Kbp, unsigned short* __restrict__ KTg) {
  __shared__ __align__(16) float4 oas[64];      // out[s] row (256 f)
  __shared__ float psum[4][64];
  const int t = blockIdx.x;
  const int tid = threadIdx.x;
  const int o = tid & 63, c = tid >> 6;         // edge o, chunk c (wave-uniform)
  const int s = t;
  if (tid < 64) oas[tid] = ((const float4*)(outE + (size_t)s * D_EMB))[tid];
  __syncthreads();
  const int d = (13 * t + o) & 1023;
  const int dn = T_NUM + d;
  {
    const float4* ob = (const float4*)(outE + (size_t)dn * D_EMB) + c * 16;
    const float4* oa = oas + c * 16;
    float dot = 0.f;
#pragma unroll
    for (int i = 0; i < 16; i++) {
      const float4 a = oa[i], bq = ob[i];
      dot += a.x * bq.x + a.y * bq.y + a.z * bq.z + a.w * bq.w;
    }
    psum[c][o] = dot;
  }
  __syncthreads();
  if (tid < 64) {
    const float dot = psum[0][o] + psum[1][o] + psum[2][o] + psum[3][o];
    const float cosv = dot / fmaxf(nrm[s] * nrm[dn], 1e-6f);
    const float4 A = ((const float4*)cov)[s];
    const float4 B = ((const float4*)cov)[dn];
    const float ltx = fmaxf(A.x, B.x), lty = fmaxf(A.y, B.y);
    const float rbx = fminf(A.z, B.z), rby = fminf(A.w, B.w);
    const float wx = fmaxf(rbx - ltx, 0.f), wy = fmaxf(rby - lty, 0.f);
    const float inter = wx * wy;
    const float areaA = (A.z - A.x) * (A.w - A.y);
    const float areaB = (B.z - B.x) * (B.w - B.y);
    const float iou = inter / (areaA + areaB - inter + 1e-9f);
    float aff = b2c[0];
#pragma unroll
    for (int jj = 0; jj < 8; jj++) {
      const float h = fmaxf(cosv * W1c[jj] + iou * W1c[8 + jj] + b1c[jj], 0.f);
      aff = fmaf(h, W2c[jj], aff);
    }
    const float Kv = __expf(aff * 5.0f);
    const int tp = (13 * s) & 1023;
    Kbp[tp * 68 + (tp & 3) + o] = Kv;
    if (o < 4) {
      const int pr = (o < (tp & 3)) ? o : o + 64;   // the 4 pad slots of row tp
      Kbp[tp * 68 + pr] = 0.f;
    }
    const int cbase = (((d & 1022) + 960) & 1023) & ~3;
    const int rho = (((d + 961) & 1023) - cbase) & 1023;   // 1..4
    KTg[d * 72 + rho + 63 - o] = (unsigned short)bf16r(Kv);
    if (o < 8) {
      const int slot = (o < rho) ? o : o + 64;      // pads: [0,rho) U [rho+64,72)
      KTg[d * 72 + slot] = 0;
    }
  }
}

// ======== Sinkhorn (block 0) + gt-copy (blocks 1..512, hidden under it).
// Block 0: 512 thr, 128 VGPR, rows 2t,2t+1 in 68 bf16x2 VGPRs; 144 KiB KT
// band staged into LDS ONCE. r11 lesson (3rd failure of the 1024-thr
// lane): register-resident sinkhorn NEEDS the 128-VGPR budget that only
// <=512-thr blocks get on this toolchain; 1024-thr = 64-VGPR cap = spill.
// This 512-thr version is the proven-best (r10: 194.4us total). ==
__global__ __launch_bounds__(512, 2) void k_sinkhorn(
    const float* __restrict__ Kbp, const unsigned short* __restrict__ KTg,
    float* __restrict__ ug, float* __restrict__ vg,
    const float* __restrict__ gt, float* __restrict__ out) {
  if (blockIdx.x != 0) {   // gt copy: blocks 1..512 x 512 thr x 1 float4
    const size_t idx = (size_t)(blockIdx.x - 1) * 512 + threadIdx.x;
    ((float4*)out)[(size_t)T_NUM * 256 + idx] = ((const float4*)gt)[idx];
    return;
  }
  __shared__ __align__(16) float u_lds[1092];   // replicated: [1024+i]=[i], i<68
  __shared__ __align__(16) float v_lds[1092];
  __shared__ float red_u[8];
  __shared__ float red_v[8];
  __shared__ __align__(16) uint4 ktlA[9][512];  // KT rows 2t   (72 bf16 each)
  __shared__ __align__(16) uint4 ktlB[9][512];  // KT rows 2t+1
  const int tid = threadIdx.x;                  // 0..511
  const int lane = tid & 63, wid = tid >> 6;
  const int ra = 2 * tid, rb = 2 * tid + 1;     // adjacent rows (t' space)
  const int qa = (ra & ~3) >> 2;                // shared row v-window base/4
  const int cbase = ((ra + 960) & 1023) & ~3;   // shared col u-window base
  const int qc = cbase >> 2;
  unsigned k0[34], k1[34];                      // 68 bf16x2 slots per row
  {
    const float4* s0p = (const float4*)(Kbp + (size_t)ra * 68);
    const float4* s1p = (const float4*)(Kbp + (size_t)rb * 68);
#pragma unroll
    for (int c = 0; c < 17; c++) {
      float4 f = s0p[c];
      k0[2 * c]     = bf16r(f.x) | (bf16r(f.y) << 16);
      k0[2 * c + 1] = bf16r(f.z) | (bf16r(f.w) << 16);
      f = s1p[c];
      k1[2 * c]     = bf16r(f.x) | (bf16r(f.y) << 16);
      k1[2 * c + 1] = bf16r(f.z) | (bf16r(f.w) << 16);
    }
  }
  {
    // stage KT band: thread reads 288 contiguous bytes (rows 2t,2t+1),
    // writes lane-contiguous LDS. One-time; coalesced; conflict-free.
    const uint4* g = (const uint4*)KTg;
#pragma unroll
    for (int q = 0; q < 9; q++) ktlA[q][tid] = g[tid * 18 + q];
#pragma unroll
    for (int q = 0; q < 9; q++) ktlB[q][tid] = g[tid * 18 + 9 + q];
  }
  float u0 = 1.f, u1 = 1.f, vc0 = 1.f, vc1 = 1.f, u_sl = 1.f, v_sl = 1.f;
  v_lds[tid] = 1.f; v_lds[tid + 512] = 1.f;
  if (tid < 68) v_lds[1024 + tid] = 1.f;
  if (tid < 8) red_v[tid] = 128.f;              // 64 lanes x 2 cols x 1.0
  const float slack = 0.36787944117144233f;     // exp(SLACK*LAM) = exp(-1)
  __syncthreads();
#pragma unroll 1
  for (int it = 0; it < 8; ++it) {
    // ---- row phase: one shared 68-slot v-window serves both rows
    const float4* vq = (const float4*)v_lds;
    float a00 = 0.f, a01 = 0.f, a10 = 0.f, a11 = 0.f;
#pragma unroll
    for (int c = 0; c < 17; c++) {
      const float4 v4 = vq[qa + c];
      unsigned p = k0[2 * c];
      a00 = fmaf(bflo(p), v4.x, a00); a00 = fmaf(bfhi(p), v4.y, a00);
      p = k0[2 * c + 1];
      a01 = fmaf(bflo(p), v4.z, a01); a01 = fmaf(bfhi(p), v4.w, a01);
      p = k1[2 * c];
      a10 = fmaf(bflo(p), v4.x, a10); a10 = fmaf(bfhi(p), v4.y, a10);
      p = k1[2 * c + 1];
      a11 = fmaf(bflo(p), v4.z, a11); a11 = fmaf(bfhi(p), v4.w, a11);
    }
    const float sumv = red_v[0] + red_v[1] + red_v[2] + red_v[3] +
                       red_v[4] + red_v[5] + red_v[6] + red_v[7];
    const float s0 = a00 + a01 + slack * v_sl;
    const float s1 = a10 + a11 + slack * v_sl;
    u0 = u0 / (u0 * s0 + 1e-9f);
    u1 = u1 / (u1 * s1 + 1e-9f);
    u_sl = u_sl / (u_sl * slack * (sumv + v_sl) + 1e-9f);
    u_lds[ra] = u0; u_lds[rb] = u1;
    if (tid < 34) { u_lds[1024 + ra] = u0; u_lds[1024 + rb] = u1; }
    float usum = u0 + u1;
#pragma unroll
    for (int o = 32; o > 0; o >>= 1) usum += __shfl_down(usum, o, 64);
    if (lane == 0) red_u[wid] = usum;
    __syncthreads();
    // ---- col phase: KT rows from LDS (conflict-free), shared u-window
    const float4* uq = (const float4*)u_lds;
    float t0 = 0.f, t1 = 0.f;
#pragma unroll 3
    for (int q = 0; q < 9; q++) {
      const uint4 A = ktlA[q][tid];
      const uint4 B = ktlB[q][tid];
      const float4 ua = uq[qc + 2 * q];
      const float4 ub = uq[qc + 2 * q + 1];
      t0 = fmaf(bflo(A.x), ua.x, t0); t0 = fmaf(bfhi(A.x), ua.y, t0);
      t0 = fmaf(bflo(A.y), ua.z, t0); t0 = fmaf(bfhi(A.y), ua.w, t0);
      t0 = fmaf(bflo(A.z), ub.x, t0); t0 = fmaf(bfhi(A.z), ub.y, t0);
      t0 = fmaf(bflo(A.w), ub.z, t0); t0 = fmaf(bfhi(A.w), ub.w, t0);
      t1 = fmaf(bflo(B.x), ua.x, t1); t1 = fmaf(bfhi(B.x), ua.y, t1);
      t1 = fmaf(bflo(B.y), ua.z, t1); t1 = fmaf(bfhi(B.y), ua.w, t1);
      t1 = fmaf(bflo(B.z), ub.x, t1); t1 = fmaf(bfhi(B.z), ub.y, t1);
      t1 = fmaf(bflo(B.w), ub.z, t1); t1 = fmaf(bfhi(B.w), ub.w, t1);
    }
    const float sumu = red_u[0] + red_u[1] + red_u[2] + red_u[3] +
                       red_u[4] + red_u[5] + red_u[6] + red_u[7];
    t0 += slack * u_sl;
    t1 += slack * u_sl;
    vc0 = vc0 / (vc0 * t0 + 1e-9f);
    vc1 = vc1 / (vc1 * t1 + 1e-9f);
    v_sl = v_sl / (v_sl * slack * (sumu + u_sl) + 1e-9f);
    v_lds[ra] = vc0; v_lds[rb] = vc1;           // col index == ra/rb values
    if (tid < 34) { v_lds[1024 + ra] = vc0; v_lds[1024 + rb] = vc1; }
    float vsum = vc0 + vc1;
#pragma unroll
    for (int o = 32; o > 0; o >>= 1) vsum += __shfl_down(vsum, o, 64);
    if (lane == 0) red_v[wid] = vsum;
    __syncthreads();
  }
  ((float2*)ug)[tid] = make_float2(u0, u1);     // rows 2t,2t+1 (t' space)
  ((float2*)vg)[tid] = make_float2(vc0, vc1);   // cols 2t,2t+1 (d space)
}

// ======== dense final write (product only; gt copy moved to k_sinkhorn) ====
__global__ __launch_bounds__(256) void k_final(
    const float* __restrict__ Kbp, const float* __restrict__ ug,
    const float* __restrict__ vg, float* __restrict__ out) {
  const int t = blockIdx.x;
  const int tp = (13 * t) & 1023;
  const float u = ug[tp];
  const float* krow = Kbp + (size_t)tp * 68 + (tp & 3);
  const int d0 = threadIdx.x * 4;
  const float4 v4 = ((const float4*)vg)[threadIdx.x];
  float4 o4;
  const int m0 = (d0 - tp) & 1023;
  const int m1 = (d0 + 1 - tp) & 1023;
  const int m2 = (d0 + 2 - tp) & 1023;
  const int m3 = (d0 + 3 - tp) & 1023;
  o4.x = (m0 < 64) ? u * krow[m0] * v4.x : 0.f;
  o4.y = (m1 < 64) ? u * krow[m1] * v4.y : 0.f;
  o4.z = (m2 < 64) ? u * krow[m2] * v4.z : 0.f;
  o4.w = (m3 < 64) ? u * krow[m3] * v4.w : 0.f;
  ((float4*)out)[(size_t)t * 256 + threadIdx.x] = o4;
  if (t == 0 && threadIdx.x == 0) {
    out[(size_t)2 * T_NUM * DET_NUM] = 1024.0f;      // det_num
    out[(size_t)2 * T_NUM * DET_NUM + 1] = 1024.0f;  // tracklet_num
  }
}

extern "C" void kernel_launch(void* const* d_in, const int* in_sizes, int n_in,
                              void* d_out, int out_size, void* d_ws, size_t ws_size,
                              hipStream_t stream) {
  const float* x      = (const float*)d_in[0];
  const float* coords = (const float*)d_in[1];
  const float* cov    = (const float*)d_in[2];
  const float* gt     = (const float*)d_in[3];
  const float* W_enc  = (const float*)d_in[5];
  const float* b_enc  = (const float*)d_in[6];
  const float* W1a    = (const float*)d_in[7];
  const float* b1a    = (const float*)d_in[8];
  const float* W2a    = (const float*)d_in[9];
  const float* b2a    = (const float*)d_in[10];
  const float* W1g    = (const float*)d_in[11];
  const float* b1g    = (const float*)d_in[12];
  const float* W2g    = (const float*)d_in[13];
  const float* b2g    = (const float*)d_in[14];
  const float* W1f    = (const float*)d_in[15];
  const float* b1f    = (const float*)d_in[16];
  const float* W2f    = (const float*)d_in[17];
  const float* b2f    = (const float*)d_in[18];
  const float* Wn     = (const float*)d_in[19];
  const float* Wm     = (const float*)d_in[20];
  const float* bo     = (const float*)d_in[21];
  const float* W1c    = (const float*)d_in[22];
  const float* b1c    = (const float*)d_in[23];
  const float* W2c    = (const float*)d_in[24];
  const float* b2c    = (const float*)d_in[25];

  char* ws = (char*)d_ws;
  size_t off = 0;
  auto alloc = [&](size_t bytes) {
    char* p = ws + off;
    off = (off + bytes + 255) & ~(size_t)255;
    return p;
  };
  float* node  = (float*)alloc((size_t)N_NODES * D_EMB * 4);
  float* P1    = (float*)alloc((size_t)N_NODES * 64 * 4);
  float* P2    = (float*)alloc((size_t)N_NODES * 64 * 4);
  float* G1    = (float*)alloc((size_t)N_NODES * 16 * 4);
  float* G2    = (float*)alloc((size_t)N_NODES * 16 * 4);
  float* outE  = (float*)alloc((size_t)N_NODES * D_EMB * 4);
  float* nrm   = (float*)alloc((size_t)N_NODES * 4);
  float* Kbp   = (float*)alloc((size_t)1024 * 68 * 4);
  unsigned short* KTg = (unsigned short*)alloc((size_t)1024 * 72 * 2);
  float* ug    = (float*)alloc(1024 * 4);
  float* vg    = (float*)alloc(1024 * 4);
  float* out   = (float*)d_out;

  k_enc_pg<<<N_NODES / 4, 512, 0, stream>>>(x, W_enc, b_enc, coords, W1a, W1g,
                                            node, P1, P2, G1, G2);
  k_msg_out<<<N_NODES / 4, 512, 0, stream>>>(node, P1, P2, G1, G2,
                                             b1a, W2a, b2a, b1g, W2g, b2g,
                                             W1f, b1f, W2f, b2f,
                                             Wn, Wm, bo, outE, nrm);
  k_aff<<<T_NUM, 256, 0, stream>>>(outE, nrm, cov, W1c, b1c, W2c, b2c,
                                   Kbp, KTg);
  k_sinkhorn<<<513, 512, 0, stream>>>(Kbp, KTg, ug, vg, gt, out);
  k_final<<<T_NUM, 256, 0, stream>>>(Kbp, ug, vg, out);
}